// Round 8
// baseline (135.376 us; speedup 1.0000x reference)
//
#include <hip/hip_runtime.h>

typedef __bf16 v8bf __attribute__((ext_vector_type(8)));
typedef __bf16 v4bf __attribute__((ext_vector_type(4)));
typedef __bf16 v2bf __attribute__((ext_vector_type(2)));
typedef float  v4f  __attribute__((ext_vector_type(4)));
typedef float  v2f  __attribute__((ext_vector_type(2)));
typedef unsigned long long u64;

namespace {

constexpr int kB = 512, kM = 4096, kH = 8;

// ws layout (bytes): wq 32KB @ 0, wk 32KB @ 32768, wfc 64KB @ 65536
// Tile swizzle: element (r, c) of a row-major [R x C] matrix lives at
//   tile = (r>>4)*(C/32) + (c>>5);  addr = tile*512 + (r&15)*32 + (c&31)

// ---------------- K0: weight casts + swizzle + zero-init of fc out region ----------------
__global__ __launch_bounds__(256) void k0_weights(
    const float* __restrict__ Wq, const float* __restrict__ Wk,
    const float* __restrict__ Wfc,
    __bf16* __restrict__ wq, __bf16* __restrict__ wk, __bf16* __restrict__ wfc,
    float* __restrict__ out) {
  int i = blockIdx.x * 256 + threadIdx.x;
  float4 z = make_float4(0.f, 0.f, 0.f, 0.f);
#pragma unroll
  for (int j = 0; j < 4; ++j) reinterpret_cast<float4*>(out)[i + j * 131072] = z;
  if (i < 16384) {
    int e = i >> 6, k = i & 63;
    int dst = ((e >> 4) * 2 + (k >> 5)) * 512 + (e & 15) * 32 + (k & 31);
    wq[dst] = (__bf16)(Wq[i] * 0.015625f);
  } else if (i < 32768) {
    int j = i - 16384;
    int e = j >> 6, k = j & 63;
    int dst = ((e >> 4) * 2 + (k >> 5)) * 512 + (e & 15) * 32 + (k & 31);
    wk[dst] = (__bf16)Wk[j];
  } else if (i < 65536) {
    int j = i - 32768;
    int o = j >> 9, f = j & 511;
    int dst = ((o >> 4) * 16 + (f >> 5)) * 512 + (o & 15) * 32 + (f & 31);
    wfc[dst] = (__bf16)Wfc[j];
  }
}

// ---------------- K1: fused kernel, 4 heads per block, 2 blocks per b ----------------
// grid (512, 2), 256 threads, LDS 36.9 KB -> 4 blocks/CU, one scheduling round.
// qGEMM hoisted; s_K double-buffered (2 barriers/head); intra-head phases reordered
// so scores/softmax/fc (dependency chains) overlap conv (issue-heavy VALU) in the
// same barrier span. attn output stored nontemporally (write-once, skip L2).
__global__ __launch_bounds__(256, 4) void k_fused(
    const float* __restrict__ feat, const int* __restrict__ sidx,
    const float* __restrict__ gamma, const float* __restrict__ beta,
    const __bf16* __restrict__ wq, const __bf16* __restrict__ wk,
    const float* __restrict__ Wv1, const float* __restrict__ Wv2,
    const __bf16* __restrict__ wfc, float* __restrict__ out) {
  __shared__ __align__(16) __bf16 smem[18432];  // 36,864 B
  __shared__ float red[4];
  __bf16* s_feat = smem;            // 4096   raw features bf16 (gather source, all heads)
  __bf16* s_kf   = smem + 4096;     // 64x72  gathered kf (conv input; pads zeroed once)
  __bf16* s_K0   = smem + 8704;     // 64x40  K[n][d], buffer 0
  __bf16* s_K1   = smem + 11264;    // 64x40  K[n][d], buffer 1
  __bf16* s_vT   = smem + 13824;    // 64x72  v^T [s][n]
  __bf16* s_qin  = smem + 4096;     // alias over s_kf: LN output, dead after prologue

  const int b = blockIdx.x, half = blockIdx.y, h0 = 4 * half;
  const int t = threadIdx.x, w = t >> 6, lane = t & 63;
  const int quad = lane >> 4, l16 = lane & 15;
  const int myrow = 16 * w + l16;  // kf/K/q/o row owned by this lane

  // ---- LN phase (+ prefetch first head's gather indices) ----
  const float4* frow4 = reinterpret_cast<const float4*>(feat + (size_t)b * kM);
  const float4* g4  = reinterpret_cast<const float4*>(gamma);
  const float4* be4 = reinterpret_cast<const float4*>(beta);
  float4 xs[4];
  float s = 0.f;
#pragma unroll
  for (int j = 0; j < 4; ++j) {
    xs[j] = frow4[t + j * 256];
    s += xs[j].x + xs[j].y + xs[j].z + xs[j].w;
  }
  int4 idxc[4];
  {
    const int* ibase = sidx + (size_t)h0 * kM + myrow * 64 + 8 * quad;
#pragma unroll
    for (int p = 0; p < 4; ++p)
      idxc[p] = *(const int4*)(ibase + 32 * (p >> 1) + 4 * (p & 1));
  }
#pragma unroll
  for (int o = 32; o > 0; o >>= 1) s += __shfl_xor(s, o);
  if (lane == 0) red[w] = s;
  __syncthreads();
  const float mu = (red[0] + red[1] + red[2] + red[3]) * (1.f / kM);
  float var_p = 0.f;
#pragma unroll
  for (int j = 0; j < 4; ++j) {
    float d0 = xs[j].x - mu, d1 = xs[j].y - mu, d2 = xs[j].z - mu, d3 = xs[j].w - mu;
    var_p += d0 * d0 + d1 * d1 + d2 * d2 + d3 * d3;
  }
#pragma unroll
  for (int o = 32; o > 0; o >>= 1) var_p += __shfl_xor(var_p, o);
  __syncthreads();
  if (lane == 0) red[w] = var_p;
  __syncthreads();
  const float var  = (red[0] + red[1] + red[2] + red[3]) * (1.f / kM);
  const float rstd = rsqrtf(var + 1e-5f);
#pragma unroll
  for (int j = 0; j < 4; ++j) {
    const int i4 = t + j * 256;
    float4 g = g4[i4], bt = be4[i4];
    v4bf fb, qb;
    fb[0] = (__bf16)xs[j].x; fb[1] = (__bf16)xs[j].y;
    fb[2] = (__bf16)xs[j].z; fb[3] = (__bf16)xs[j].w;
    qb[0] = (__bf16)((xs[j].x - mu) * rstd * g.x + bt.x);
    qb[1] = (__bf16)((xs[j].y - mu) * rstd * g.y + bt.y);
    qb[2] = (__bf16)((xs[j].z - mu) * rstd * g.z + bt.z);
    qb[3] = (__bf16)((xs[j].w - mu) * rstd * g.w + bt.w);
    *(v4bf*)(s_feat + 4 * i4) = fb;
    const int n = i4 >> 4, k = 4 * (t & 15);
    const int dst = ((n >> 4) * 2 + (k >> 5)) * 512 + (n & 15) * 32 + (k & 31);
    *(v4bf*)(s_qin + dst) = qb;
  }
  __syncthreads();  // bar0: s_feat + s_qin ready

  // ---- prologue qGEMM for ALL 4 heads (A-operand is head-invariant) ----
  const int qs = 16 * (2 * (quad & 1));
  v8bf aq[4];
  {
    v8bf aA0 = *(const v8bf*)(s_qin + (2 * w + 0) * 512 + l16 * 32 + 8 * quad);
    v8bf aA1 = *(const v8bf*)(s_qin + (2 * w + 1) * 512 + l16 * 32 + 8 * quad);
#pragma unroll
    for (int itq = 0; itq < 4; ++itq) {
      const int h = h0 + itq;
      v4f dq0 = {0.f, 0.f, 0.f, 0.f}, dq1 = {0.f, 0.f, 0.f, 0.f};
      v8bf b00 = *(const v8bf*)(wq + (size_t)(4 * h + 0) * 512 + l16 * 32 + 8 * quad);
      v8bf b01 = *(const v8bf*)(wq + (size_t)(4 * h + 1) * 512 + l16 * 32 + 8 * quad);
      v8bf b10 = *(const v8bf*)(wq + (size_t)(4 * h + 2) * 512 + l16 * 32 + 8 * quad);
      v8bf b11 = *(const v8bf*)(wq + (size_t)(4 * h + 3) * 512 + l16 * 32 + 8 * quad);
      dq0 = __builtin_amdgcn_mfma_f32_16x16x32_bf16(b00, aA0, dq0, 0, 0, 0);
      dq0 = __builtin_amdgcn_mfma_f32_16x16x32_bf16(b01, aA1, dq0, 0, 0, 0);
      dq1 = __builtin_amdgcn_mfma_f32_16x16x32_bf16(b10, aA0, dq1, 0, 0, 0);
      dq1 = __builtin_amdgcn_mfma_f32_16x16x32_bf16(b11, aA1, dq1, 0, 0, 0);
      v4bf p0, p1;
#pragma unroll
      for (int r = 0; r < 4; ++r) { p0[r] = (__bf16)dq0[r]; p1[r] = (__bf16)dq1[r]; }
      const u64 P0 = __builtin_bit_cast(u64, p0), P1 = __builtin_bit_cast(u64, p1);
      u64 s0p0 = __shfl(P0, l16 + qs),      s0p1 = __shfl(P1, l16 + qs);
      u64 s1p0 = __shfl(P0, l16 + qs + 16), s1p1 = __shfl(P1, l16 + qs + 16);
      v4bf lo = __builtin_bit_cast(v4bf, (quad >> 1) ? s0p1 : s0p0);
      v4bf hi = __builtin_bit_cast(v4bf, (quad >> 1) ? s1p1 : s1p0);
#pragma unroll
      for (int r = 0; r < 4; ++r) { aq[itq][r] = lo[r]; aq[itq][4 + r] = hi[r]; }
    }
  }

  // ---- gather head 0 into registers (s_feat ready since bar0)
  v8bf g0, g1;
  g0[0] = s_feat[idxc[0].x]; g0[1] = s_feat[idxc[0].y];
  g0[2] = s_feat[idxc[0].z]; g0[3] = s_feat[idxc[0].w];
  g0[4] = s_feat[idxc[1].x]; g0[5] = s_feat[idxc[1].y];
  g0[6] = s_feat[idxc[1].z]; g0[7] = s_feat[idxc[1].w];
  g1[0] = s_feat[idxc[2].x]; g1[1] = s_feat[idxc[2].y];
  g1[2] = s_feat[idxc[2].z]; g1[3] = s_feat[idxc[2].w];
  g1[4] = s_feat[idxc[3].x]; g1[5] = s_feat[idxc[3].y];
  g1[6] = s_feat[idxc[3].z]; g1[7] = s_feat[idxc[3].w];
  __syncthreads();  // bar0b: all s_qin reads done; s_kf region reusable

  // conv pad cols 64..71: zero once (region was s_qin-aliased, so after bar0b)
  if (t < 64) { v8bf z = {}; *(v8bf*)(s_kf + t * 72 + 64) = z; }

  v4f acc[4] = {{0.f, 0.f, 0.f, 0.f}, {0.f, 0.f, 0.f, 0.f},
                {0.f, 0.f, 0.f, 0.f}, {0.f, 0.f, 0.f, 0.f}};  // fc partial (this half)
  v4bf Qprev[4];

  for (int it = 0; it < 4; ++it) {
    const int h = h0 + it;
    __bf16* s_K = (it & 1) ? s_K1 : s_K0;

    // ---- staging: dump gather regs to s_kf (conv input), K-GEMM from regs
    *(v8bf*)(s_kf + myrow * 72 + 8 * quad)      = g0;
    *(v8bf*)(s_kf + myrow * 72 + 32 + 8 * quad) = g1;
    {
      v4f dk0 = {0.f, 0.f, 0.f, 0.f}, dk1 = {0.f, 0.f, 0.f, 0.f};
      v8bf b00 = *(const v8bf*)(wk + (size_t)(4 * h + 0) * 512 + l16 * 32 + 8 * quad);
      v8bf b10 = *(const v8bf*)(wk + (size_t)(4 * h + 2) * 512 + l16 * 32 + 8 * quad);
      dk0 = __builtin_amdgcn_mfma_f32_16x16x32_bf16(b00, g0, dk0, 0, 0, 0);
      dk1 = __builtin_amdgcn_mfma_f32_16x16x32_bf16(b10, g0, dk1, 0, 0, 0);
      v8bf b01 = *(const v8bf*)(wk + (size_t)(4 * h + 1) * 512 + l16 * 32 + 8 * quad);
      v8bf b11 = *(const v8bf*)(wk + (size_t)(4 * h + 3) * 512 + l16 * 32 + 8 * quad);
      dk0 = __builtin_amdgcn_mfma_f32_16x16x32_bf16(b01, g1, dk0, 0, 0, 0);
      dk1 = __builtin_amdgcn_mfma_f32_16x16x32_bf16(b11, g1, dk1, 0, 0, 0);
      v4bf p0, p1;
#pragma unroll
      for (int r = 0; r < 4; ++r) { p0[r] = (__bf16)dk0[r]; p1[r] = (__bf16)dk1[r]; }
      *(v4bf*)(s_K + myrow * 40 + 4 * quad)      = p0;
      *(v4bf*)(s_K + myrow * 40 + 16 + 4 * quad) = p1;
    }
    __syncthreads();  // bar1: s_kf + s_K[it&1] ready; prev head's PV/scores reads all done

    // ================== bar1 -> bar2 span: dependency chains ∥ conv ==================

    // ---- next head's gather index loads (global; issued early, long latency)
    int4 ixn[4];
    if (it < 3) {
      const int* ibase = sidx + (size_t)(h + 1) * kM + myrow * 64 + 8 * quad;
#pragma unroll
      for (int p = 0; p < 4; ++p)
        ixn[p] = *(const int4*)(ibase + 32 * (p >> 1) + 4 * (p & 1));
    }

    // ---- scores, swapped: sc[nt][r] = scores[qi=myrow][n=16nt+4quad+r] (row-local)
    v4f sc[4];
#pragma unroll
    for (int nt = 0; nt < 4; ++nt) {
      v4f zz = {0.f, 0.f, 0.f, 0.f};
      v8bf bbK = *(const v8bf*)(s_K + (16 * nt + l16) * 40 + 8 * quad);
      sc[nt] = __builtin_amdgcn_mfma_f32_16x16x32_bf16(bbK, aq[it], zz, 0, 0, 0);
    }

    // ---- softmax fully in registers
    float mx = sc[0][0];
#pragma unroll
    for (int nt = 0; nt < 4; ++nt)
#pragma unroll
      for (int r = 0; r < 4; ++r) mx = fmaxf(mx, sc[nt][r]);
    mx = fmaxf(mx, __shfl_xor(mx, 16));
    mx = fmaxf(mx, __shfl_xor(mx, 32));
    float ssum = 0.f;
#pragma unroll
    for (int nt = 0; nt < 4; ++nt)
#pragma unroll
      for (int r = 0; r < 4; ++r) {
        float e = __expf(sc[nt][r] - mx);
        sc[nt][r] = e; ssum += e;
      }
    ssum += __shfl_xor(ssum, 16);
    ssum += __shfl_xor(ssum, 32);
    const float inv = 1.0f / ssum;
#pragma unroll
    for (int nt = 0; nt < 4; ++nt) sc[nt] *= inv;

    // ---- attn output: nontemporal f32 stores (write-once, bypass L2)
    float* attn_out = out + (size_t)kB * kM + ((size_t)(b * kH + h)) * 4096;
#pragma unroll
    for (int nt = 0; nt < 4; ++nt)
      __builtin_nontemporal_store(sc[nt], (v4f*)(attn_out + myrow * 64 + 16 * nt + 4 * quad));

    // ---- pack attn to bf16 for PV
    v4bf P[4];
#pragma unroll
    for (int nt = 0; nt < 4; ++nt)
#pragma unroll
      for (int r = 0; r < 4; ++r) P[nt][r] = (__bf16)sc[nt][r];

    // ---- fc for previous head (registers + global wfc only): overlaps conv
    if (it > 0) {
      const int hp = h - 1;
#pragma unroll
      for (int kt = 0; kt < 2; ++kt) {
        const u64 qA = __builtin_bit_cast(u64, Qprev[2 * kt]);
        const u64 qB = __builtin_bit_cast(u64, Qprev[2 * kt + 1]);
        u64 A0 = __shfl(qA, l16 + qs), A1 = __shfl(qA, l16 + qs + 16);
        u64 B0 = __shfl(qB, l16 + qs), B1 = __shfl(qB, l16 + qs + 16);
        v4bf lo = __builtin_bit_cast(v4bf, (quad >> 1) ? B0 : A0);
        v4bf hi = __builtin_bit_cast(v4bf, (quad >> 1) ? B1 : A1);
        v8bf a_fc;
#pragma unroll
        for (int r = 0; r < 4; ++r) { a_fc[r] = lo[r]; a_fc[4 + r] = hi[r]; }
#pragma unroll
        for (int nt = 0; nt < 4; ++nt) {
          v8bf bb = *(const v8bf*)(wfc + (size_t)(nt * 16 + hp * 2 + kt) * 512 + l16 * 32 + 8 * quad);
          acc[nt] = __builtin_amdgcn_mfma_f32_16x16x32_bf16(a_fc, bb, acc[nt], 0, 0, 0);
        }
      }
    }

    // ---- windowed conv + relu + residual, float2-packed, vT[s][n]
    {
      const int n = lane, p0c = w * 16;
      float w1[4][3], w2[4];
#pragma unroll
      for (int d = 0; d < 4; ++d) {
#pragma unroll
        for (int c = 0; c < 3; ++c) w1[d][c] = Wv1[(h * 4 + d) * 3 + c];
        w2[d] = Wv2[h * 4 + d];
      }
      v8bf xa = *(const v8bf*)(s_kf + n * 72 + p0c);
      v8bf xb = *(const v8bf*)(s_kf + n * 72 + p0c + 8);
      v2bf xc = *(const v2bf*)(s_kf + n * 72 + p0c + 16);  // pad cols zeroed once
      v2f x2[10];
#pragma unroll
      for (int j = 0; j < 8; ++j) { x2[j][0] = (float)xa[j]; x2[j][1] = (float)xb[j]; }
      x2[8][0] = (float)xb[0]; x2[8][1] = (float)xc[0];
      x2[9][0] = (float)xb[1]; x2[9][1] = (float)xc[1];
      const v2f z2 = {0.f, 0.f};
#pragma unroll
      for (int pp = 0; pp < 8; ++pp) {
        v2f a2 = x2[pp];
#pragma unroll
        for (int d = 0; d < 4; ++d) {
          v2f v1 = x2[pp] * w1[d][0] + x2[pp + 1] * w1[d][1] + x2[pp + 2] * w1[d][2];
          v1 = __builtin_elementwise_max(v1, z2);
          a2 = a2 + v1 * w2[d];
        }
        s_vT[(p0c + pp) * 72 + n]     = (__bf16)a2[0];
        s_vT[(p0c + pp + 8) * 72 + n] = (__bf16)a2[1];
      }
    }

    // ---- next head's gather from s_feat (latency hidden under bar2 + PV)
    if (it < 3) {
      g0[0] = s_feat[ixn[0].x]; g0[1] = s_feat[ixn[0].y];
      g0[2] = s_feat[ixn[0].z]; g0[3] = s_feat[ixn[0].w];
      g0[4] = s_feat[ixn[1].x]; g0[5] = s_feat[ixn[1].y];
      g0[6] = s_feat[ixn[1].z]; g0[7] = s_feat[ixn[1].w];
      g1[0] = s_feat[ixn[2].x]; g1[1] = s_feat[ixn[2].y];
      g1[2] = s_feat[ixn[2].z]; g1[3] = s_feat[ixn[2].w];
      g1[4] = s_feat[ixn[3].x]; g1[5] = s_feat[ixn[3].y];
      g1[6] = s_feat[ixn[3].z]; g1[7] = s_feat[ixn[3].w];
    }
    __syncthreads();  // bar2: s_vT ready

    // ---- PV: swapped, dOT[st] = o[qi=myrow][s=16st+4quad+r] (row-local)
    v4f dOT[4] = {{0.f, 0.f, 0.f, 0.f}, {0.f, 0.f, 0.f, 0.f},
                  {0.f, 0.f, 0.f, 0.f}, {0.f, 0.f, 0.f, 0.f}};
#pragma unroll
    for (int kt = 0; kt < 2; ++kt) {
      const u64 pA = __builtin_bit_cast(u64, P[2 * kt]);
      const u64 pB = __builtin_bit_cast(u64, P[2 * kt + 1]);
      u64 A0 = __shfl(pA, l16 + qs), A1 = __shfl(pA, l16 + qs + 16);
      u64 B0 = __shfl(pB, l16 + qs), B1 = __shfl(pB, l16 + qs + 16);
      v4bf lo = __builtin_bit_cast(v4bf, (quad >> 1) ? B0 : A0);
      v4bf hi = __builtin_bit_cast(v4bf, (quad >> 1) ? B1 : A1);
      v8bf a_pv;
#pragma unroll
      for (int r = 0; r < 4; ++r) { a_pv[r] = lo[r]; a_pv[4 + r] = hi[r]; }
#pragma unroll
      for (int st = 0; st < 4; ++st) {
        v8bf bb = *(const v8bf*)(s_vT + (16 * st + l16) * 72 + 32 * kt + 8 * quad);
        dOT[st] = __builtin_amdgcn_mfma_f32_16x16x32_bf16(bb, a_pv, dOT[st], 0, 0, 0);
      }
    }
    // pack o for fc (consumed next iteration / after loop)
#pragma unroll
    for (int st = 0; st < 4; ++st)
#pragma unroll
      for (int r = 0; r < 4; ++r) Qprev[st][r] = (__bf16)dOT[st][r];
    // no tail barrier: next head's writes touch s_kf (no readers here) and the
    // other s_K buffer; s_vT is fenced by next head's bar2 span ordering.
  }

  // ---- fc for last head
  {
    const int hp = h0 + 3;
#pragma unroll
    for (int kt = 0; kt < 2; ++kt) {
      const u64 qA = __builtin_bit_cast(u64, Qprev[2 * kt]);
      const u64 qB = __builtin_bit_cast(u64, Qprev[2 * kt + 1]);
      u64 A0 = __shfl(qA, l16 + qs), A1 = __shfl(qA, l16 + qs + 16);
      u64 B0 = __shfl(qB, l16 + qs), B1 = __shfl(qB, l16 + qs + 16);
      v4bf lo = __builtin_bit_cast(v4bf, (quad >> 1) ? B0 : A0);
      v4bf hi = __builtin_bit_cast(v4bf, (quad >> 1) ? B1 : A1);
      v8bf a_fc;
#pragma unroll
      for (int r = 0; r < 4; ++r) { a_fc[r] = lo[r]; a_fc[4 + r] = hi[r]; }
#pragma unroll
      for (int nt = 0; nt < 4; ++nt) {
        v8bf bb = *(const v8bf*)(wfc + (size_t)(nt * 16 + hp * 2 + kt) * 512 + l16 * 32 + 8 * quad);
        acc[nt] = __builtin_amdgcn_mfma_f32_16x16x32_bf16(a_fc, bb, acc[nt], 0, 0, 0);
      }
    }
  }

  // ---- combine fc partials across the two half-blocks via atomicAdd (out pre-zeroed by k0)
  float* orow = out + (size_t)b * kM;
#pragma unroll
  for (int nt = 0; nt < 4; ++nt)
#pragma unroll
    for (int r = 0; r < 4; ++r)
      atomicAdd(&orow[(16 * w + 4 * quad + r) * 64 + 16 * nt + l16], acc[nt][r]);
}

}  // namespace

extern "C" void kernel_launch(void* const* d_in, const int* in_sizes, int n_in,
                              void* d_out, int out_size, void* d_ws, size_t ws_size,
                              hipStream_t stream) {
  (void)in_sizes; (void)n_in; (void)out_size; (void)ws_size;
  const float* features = (const float*)d_in[0];
  const int*   sidx     = (const int*)d_in[1];
  const float* gamma    = (const float*)d_in[2];
  const float* beta     = (const float*)d_in[3];
  const float* Wq       = (const float*)d_in[4];
  const float* Wk       = (const float*)d_in[5];
  const float* Wv1      = (const float*)d_in[6];
  const float* Wv2      = (const float*)d_in[7];
  const float* Wfc      = (const float*)d_in[8];
  float* out = (float*)d_out;

  char* ws = (char*)d_ws;
  __bf16* ws_wq  = (__bf16*)(ws);
  __bf16* ws_wk  = (__bf16*)(ws + 32768);
  __bf16* ws_wfc = (__bf16*)(ws + 65536);

  hipLaunchKernelGGL(k0_weights, dim3(512), dim3(256), 0, stream,
                     Wq, Wk, Wfc, ws_wq, ws_wk, ws_wfc, out);
  hipLaunchKernelGGL(k_fused, dim3(kB, 2), dim3(256), 0, stream,
                     features, sidx, gamma, beta, ws_wq, ws_wk, Wv1, Wv2, ws_wfc, out);
}

// Round 9
// 129.214 us; speedup vs baseline: 1.0477x; 1.0477x over previous
//
#include <hip/hip_runtime.h>

typedef __bf16 v8bf __attribute__((ext_vector_type(8)));
typedef __bf16 v4bf __attribute__((ext_vector_type(4)));
typedef __bf16 v2bf __attribute__((ext_vector_type(2)));
typedef float  v4f  __attribute__((ext_vector_type(4)));
typedef float  v2f  __attribute__((ext_vector_type(2)));
typedef unsigned long long u64;

namespace {

constexpr int kB = 512, kM = 4096, kH = 8;

// ws layout (bytes): wq 32KB @ 0, wk 32KB @ 32768, wfc 64KB @ 65536
// Tile swizzle: element (r, c) of a row-major [R x C] matrix lives at
//   tile = (r>>4)*(C/32) + (c>>5);  addr = tile*512 + (r&15)*32 + (c&31)

// ---------------- K0: weight casts + swizzle + zero-init of fc out region ----------------
__global__ __launch_bounds__(256) void k0_weights(
    const float* __restrict__ Wq, const float* __restrict__ Wk,
    const float* __restrict__ Wfc,
    __bf16* __restrict__ wq, __bf16* __restrict__ wk, __bf16* __restrict__ wfc,
    float* __restrict__ out) {
  int i = blockIdx.x * 256 + threadIdx.x;
  float4 z = make_float4(0.f, 0.f, 0.f, 0.f);
#pragma unroll
  for (int j = 0; j < 4; ++j) reinterpret_cast<float4*>(out)[i + j * 131072] = z;
  if (i < 16384) {
    int e = i >> 6, k = i & 63;
    int dst = ((e >> 4) * 2 + (k >> 5)) * 512 + (e & 15) * 32 + (k & 31);
    wq[dst] = (__bf16)(Wq[i] * 0.015625f);
  } else if (i < 32768) {
    int j = i - 16384;
    int e = j >> 6, k = j & 63;
    int dst = ((e >> 4) * 2 + (k >> 5)) * 512 + (e & 15) * 32 + (k & 31);
    wk[dst] = (__bf16)Wk[j];
  } else if (i < 65536) {
    int j = i - 32768;
    int o = j >> 9, f = j & 511;
    int dst = ((o >> 4) * 16 + (f >> 5)) * 512 + (o & 15) * 32 + (f & 31);
    wfc[dst] = (__bf16)Wfc[j];
  }
}

// ---------------- K1: fused kernel, 4 heads per block, 2 blocks per b ----------------
// grid (512, 2), 256 threads, LDS 36.9 KB -> 4 blocks/CU, one scheduling round.
// qGEMM hoisted; s_K double-buffered (2 barriers/head); scores/softmax/fc overlap conv
// in the bar1->bar2 span; stage(h+1) software-pipelined ahead of PV(h); fused LN
// reduction (1 prologue barrier); wfc kt=0 fragments issued early in the span.
__global__ __launch_bounds__(256, 4) void k_fused(
    const float* __restrict__ feat, const int* __restrict__ sidx,
    const float* __restrict__ gamma, const float* __restrict__ beta,
    const __bf16* __restrict__ wq, const __bf16* __restrict__ wk,
    const float* __restrict__ Wv1, const float* __restrict__ Wv2,
    const __bf16* __restrict__ wfc, float* __restrict__ out) {
  __shared__ __align__(16) __bf16 smem[18432];  // 36,864 B
  __shared__ float red[8];
  __bf16* s_feat = smem;            // 4096   raw features bf16 (gather source, all heads)
  __bf16* s_kf   = smem + 4096;     // 64x72  gathered kf (conv input; pads zeroed once)
  __bf16* s_K0   = smem + 8704;     // 64x40  K[n][d], buffer 0
  __bf16* s_K1   = smem + 11264;    // 64x40  K[n][d], buffer 1
  __bf16* s_vT   = smem + 13824;    // 64x72  v^T [s][n]
  __bf16* s_qin  = smem + 4096;     // alias over s_kf: LN output, dead after prologue

  const int b = blockIdx.x, half = blockIdx.y, h0 = 4 * half;
  const int t = threadIdx.x, w = t >> 6, lane = t & 63;
  const int quad = lane >> 4, l16 = lane & 15;
  const int myrow = 16 * w + l16;  // kf/K/q/o row owned by this lane

  // ---- LN phase: fused (sum, sumsq) reduction; + first head's gather indices ----
  const float4* frow4 = reinterpret_cast<const float4*>(feat + (size_t)b * kM);
  const float4* g4  = reinterpret_cast<const float4*>(gamma);
  const float4* be4 = reinterpret_cast<const float4*>(beta);
  float4 xs[4];
  float s = 0.f, s2 = 0.f;
#pragma unroll
  for (int j = 0; j < 4; ++j) {
    xs[j] = frow4[t + j * 256];
    s  += xs[j].x + xs[j].y + xs[j].z + xs[j].w;
    s2 += xs[j].x * xs[j].x + xs[j].y * xs[j].y
        + xs[j].z * xs[j].z + xs[j].w * xs[j].w;
  }
  int4 idxc[4];
  {
    const int* ibase = sidx + (size_t)h0 * kM + myrow * 64 + 8 * quad;
#pragma unroll
    for (int p = 0; p < 4; ++p)
      idxc[p] = *(const int4*)(ibase + 32 * (p >> 1) + 4 * (p & 1));
  }
#pragma unroll
  for (int o = 32; o > 0; o >>= 1) { s += __shfl_xor(s, o); s2 += __shfl_xor(s2, o); }
  if (lane == 0) { red[w] = s; red[4 + w] = s2; }
  __syncthreads();
  const float mu = (red[0] + red[1] + red[2] + red[3]) * (1.f / kM);
  const float ms = (red[4] + red[5] + red[6] + red[7]) * (1.f / kM);
  const float rstd = rsqrtf(ms - mu * mu + 1e-5f);
#pragma unroll
  for (int j = 0; j < 4; ++j) {
    const int i4 = t + j * 256;
    float4 g = g4[i4], bt = be4[i4];
    v4bf fb, qb;
    fb[0] = (__bf16)xs[j].x; fb[1] = (__bf16)xs[j].y;
    fb[2] = (__bf16)xs[j].z; fb[3] = (__bf16)xs[j].w;
    qb[0] = (__bf16)((xs[j].x - mu) * rstd * g.x + bt.x);
    qb[1] = (__bf16)((xs[j].y - mu) * rstd * g.y + bt.y);
    qb[2] = (__bf16)((xs[j].z - mu) * rstd * g.z + bt.z);
    qb[3] = (__bf16)((xs[j].w - mu) * rstd * g.w + bt.w);
    *(v4bf*)(s_feat + 4 * i4) = fb;
    const int n = i4 >> 4, k = 4 * (t & 15);
    const int dst = ((n >> 4) * 2 + (k >> 5)) * 512 + (n & 15) * 32 + (k & 31);
    *(v4bf*)(s_qin + dst) = qb;
  }
  __syncthreads();  // bar0: s_feat + s_qin ready

  // ---- prologue qGEMM for ALL 4 heads (A-operand is head-invariant) ----
  const int qs = 16 * (2 * (quad & 1));
  v8bf aq[4];
  {
    v8bf aA0 = *(const v8bf*)(s_qin + (2 * w + 0) * 512 + l16 * 32 + 8 * quad);
    v8bf aA1 = *(const v8bf*)(s_qin + (2 * w + 1) * 512 + l16 * 32 + 8 * quad);
#pragma unroll
    for (int itq = 0; itq < 4; ++itq) {
      const int h = h0 + itq;
      v4f dq0 = {0.f, 0.f, 0.f, 0.f}, dq1 = {0.f, 0.f, 0.f, 0.f};
      v8bf b00 = *(const v8bf*)(wq + (size_t)(4 * h + 0) * 512 + l16 * 32 + 8 * quad);
      v8bf b01 = *(const v8bf*)(wq + (size_t)(4 * h + 1) * 512 + l16 * 32 + 8 * quad);
      v8bf b10 = *(const v8bf*)(wq + (size_t)(4 * h + 2) * 512 + l16 * 32 + 8 * quad);
      v8bf b11 = *(const v8bf*)(wq + (size_t)(4 * h + 3) * 512 + l16 * 32 + 8 * quad);
      dq0 = __builtin_amdgcn_mfma_f32_16x16x32_bf16(b00, aA0, dq0, 0, 0, 0);
      dq0 = __builtin_amdgcn_mfma_f32_16x16x32_bf16(b01, aA1, dq0, 0, 0, 0);
      dq1 = __builtin_amdgcn_mfma_f32_16x16x32_bf16(b10, aA0, dq1, 0, 0, 0);
      dq1 = __builtin_amdgcn_mfma_f32_16x16x32_bf16(b11, aA1, dq1, 0, 0, 0);
      v4bf p0, p1;
#pragma unroll
      for (int r = 0; r < 4; ++r) { p0[r] = (__bf16)dq0[r]; p1[r] = (__bf16)dq1[r]; }
      const u64 P0 = __builtin_bit_cast(u64, p0), P1 = __builtin_bit_cast(u64, p1);
      u64 s0p0 = __shfl(P0, l16 + qs),      s0p1 = __shfl(P1, l16 + qs);
      u64 s1p0 = __shfl(P0, l16 + qs + 16), s1p1 = __shfl(P1, l16 + qs + 16);
      v4bf lo = __builtin_bit_cast(v4bf, (quad >> 1) ? s0p1 : s0p0);
      v4bf hi = __builtin_bit_cast(v4bf, (quad >> 1) ? s1p1 : s1p0);
#pragma unroll
      for (int r = 0; r < 4; ++r) { aq[itq][r] = lo[r]; aq[itq][4 + r] = hi[r]; }
    }
  }

  // ---- gather head 0 into registers (s_feat ready since bar0)
  v8bf g0, g1;
  g0[0] = s_feat[idxc[0].x]; g0[1] = s_feat[idxc[0].y];
  g0[2] = s_feat[idxc[0].z]; g0[3] = s_feat[idxc[0].w];
  g0[4] = s_feat[idxc[1].x]; g0[5] = s_feat[idxc[1].y];
  g0[6] = s_feat[idxc[1].z]; g0[7] = s_feat[idxc[1].w];
  g1[0] = s_feat[idxc[2].x]; g1[1] = s_feat[idxc[2].y];
  g1[2] = s_feat[idxc[2].z]; g1[3] = s_feat[idxc[2].w];
  g1[4] = s_feat[idxc[3].x]; g1[5] = s_feat[idxc[3].y];
  g1[6] = s_feat[idxc[3].z]; g1[7] = s_feat[idxc[3].w];
  __syncthreads();  // bar0b: all s_qin reads done; s_kf region reusable

  // conv pad cols 64..71: zero once (region was s_qin-aliased, so after bar0b)
  if (t < 64) { v8bf z = {}; *(v8bf*)(s_kf + t * 72 + 64) = z; }

  // stage: dump gather regs to s_kf (conv input) + K-GEMM from regs into sKdst
  auto stage = [&](int hh, __bf16* sKdst) {
    *(v8bf*)(s_kf + myrow * 72 + 8 * quad)      = g0;
    *(v8bf*)(s_kf + myrow * 72 + 32 + 8 * quad) = g1;
    v4f dk0 = {0.f, 0.f, 0.f, 0.f}, dk1 = {0.f, 0.f, 0.f, 0.f};
    v8bf b00 = *(const v8bf*)(wk + (size_t)(4 * hh + 0) * 512 + l16 * 32 + 8 * quad);
    v8bf b10 = *(const v8bf*)(wk + (size_t)(4 * hh + 2) * 512 + l16 * 32 + 8 * quad);
    dk0 = __builtin_amdgcn_mfma_f32_16x16x32_bf16(b00, g0, dk0, 0, 0, 0);
    dk1 = __builtin_amdgcn_mfma_f32_16x16x32_bf16(b10, g0, dk1, 0, 0, 0);
    v8bf b01 = *(const v8bf*)(wk + (size_t)(4 * hh + 1) * 512 + l16 * 32 + 8 * quad);
    v8bf b11 = *(const v8bf*)(wk + (size_t)(4 * hh + 3) * 512 + l16 * 32 + 8 * quad);
    dk0 = __builtin_amdgcn_mfma_f32_16x16x32_bf16(b01, g1, dk0, 0, 0, 0);
    dk1 = __builtin_amdgcn_mfma_f32_16x16x32_bf16(b11, g1, dk1, 0, 0, 0);
    v4bf p0, p1;
#pragma unroll
    for (int r = 0; r < 4; ++r) { p0[r] = (__bf16)dk0[r]; p1[r] = (__bf16)dk1[r]; }
    *(v4bf*)(sKdst + myrow * 40 + 4 * quad)      = p0;
    *(v4bf*)(sKdst + myrow * 40 + 16 + 4 * quad) = p1;
  };

  stage(h0, s_K0);  // head 0 staged in prologue

  v4f acc[4] = {{0.f, 0.f, 0.f, 0.f}, {0.f, 0.f, 0.f, 0.f},
                {0.f, 0.f, 0.f, 0.f}, {0.f, 0.f, 0.f, 0.f}};  // fc partial (this half)
  v4bf Qprev[4];

  for (int it = 0; it < 4; ++it) {
    const int h = h0 + it;
    __bf16* s_K = (it & 1) ? s_K1 : s_K0;
    __syncthreads();  // bar1: s_kf + s_K[it&1] ready; prev head's PV/scores reads done

    // ================== bar1 -> bar2 span: dependency chains ∥ conv ==================

    // ---- next head's gather index loads (global; issued early, long latency)
    int4 ixn[4];
    if (it < 3) {
      const int* ibase = sidx + (size_t)(h + 1) * kM + myrow * 64 + 8 * quad;
#pragma unroll
      for (int p = 0; p < 4; ++p)
        ixn[p] = *(const int4*)(ibase + 32 * (p >> 1) + 4 * (p & 1));
    }

    // ---- scores, swapped: sc[nt][r] = scores[qi=myrow][n=16nt+4quad+r] (row-local)
    v4f sc[4];
#pragma unroll
    for (int nt = 0; nt < 4; ++nt) {
      v4f zz = {0.f, 0.f, 0.f, 0.f};
      v8bf bbK = *(const v8bf*)(s_K + (16 * nt + l16) * 40 + 8 * quad);
      sc[nt] = __builtin_amdgcn_mfma_f32_16x16x32_bf16(bbK, aq[it], zz, 0, 0, 0);
    }

    // ---- early issue: fc(h-1) kt=0 wfc fragments (L2 latency hides under softmax+conv)
    v8bf wf0[4];
    if (it > 0) {
      const int hp = h - 1;
#pragma unroll
      for (int nt = 0; nt < 4; ++nt)
        wf0[nt] = *(const v8bf*)(wfc + (size_t)(nt * 16 + hp * 2) * 512 + l16 * 32 + 8 * quad);
    }

    // ---- softmax fully in registers
    float mx = sc[0][0];
#pragma unroll
    for (int nt = 0; nt < 4; ++nt)
#pragma unroll
      for (int r = 0; r < 4; ++r) mx = fmaxf(mx, sc[nt][r]);
    mx = fmaxf(mx, __shfl_xor(mx, 16));
    mx = fmaxf(mx, __shfl_xor(mx, 32));
    float ssum = 0.f;
#pragma unroll
    for (int nt = 0; nt < 4; ++nt)
#pragma unroll
      for (int r = 0; r < 4; ++r) {
        float e = __expf(sc[nt][r] - mx);
        sc[nt][r] = e; ssum += e;
      }
    ssum += __shfl_xor(ssum, 16);
    ssum += __shfl_xor(ssum, 32);
    const float inv = 1.0f / ssum;
#pragma unroll
    for (int nt = 0; nt < 4; ++nt) sc[nt] *= inv;

    // ---- attn output: plain f32 stores (NT store regressed: +11MB HBM writes)
    float* attn_out = out + (size_t)kB * kM + ((size_t)(b * kH + h)) * 4096;
#pragma unroll
    for (int nt = 0; nt < 4; ++nt)
      *(v4f*)(attn_out + myrow * 64 + 16 * nt + 4 * quad) = sc[nt];

    // ---- pack attn to bf16 for PV
    v4bf P[4];
#pragma unroll
    for (int nt = 0; nt < 4; ++nt)
#pragma unroll
      for (int r = 0; r < 4; ++r) P[nt][r] = (__bf16)sc[nt][r];

    // ---- windowed conv + relu + residual, float2-packed, vT[s][n]
    {
      const int n = lane, p0c = w * 16;
      float w1[4][3], w2[4];
#pragma unroll
      for (int d = 0; d < 4; ++d) {
#pragma unroll
        for (int c = 0; c < 3; ++c) w1[d][c] = Wv1[(h * 4 + d) * 3 + c];
        w2[d] = Wv2[h * 4 + d];
      }
      v8bf xa = *(const v8bf*)(s_kf + n * 72 + p0c);
      v8bf xb = *(const v8bf*)(s_kf + n * 72 + p0c + 8);
      v2bf xc = *(const v2bf*)(s_kf + n * 72 + p0c + 16);  // pad cols zeroed once
      v2f x2[10];
#pragma unroll
      for (int j = 0; j < 8; ++j) { x2[j][0] = (float)xa[j]; x2[j][1] = (float)xb[j]; }
      x2[8][0] = (float)xb[0]; x2[8][1] = (float)xc[0];
      x2[9][0] = (float)xb[1]; x2[9][1] = (float)xc[1];
      const v2f z2 = {0.f, 0.f};
#pragma unroll
      for (int pp = 0; pp < 8; ++pp) {
        v2f a2 = x2[pp];
#pragma unroll
        for (int d = 0; d < 4; ++d) {
          v2f v1 = x2[pp] * w1[d][0] + x2[pp + 1] * w1[d][1] + x2[pp + 2] * w1[d][2];
          v1 = __builtin_elementwise_max(v1, z2);
          a2 = a2 + v1 * w2[d];
        }
        s_vT[(p0c + pp) * 72 + n]     = (__bf16)a2[0];
        s_vT[(p0c + pp + 8) * 72 + n] = (__bf16)a2[1];
      }
    }

    // ---- fc for previous head: kt=0 uses prefetched wf0, kt=1 loads inline
    if (it > 0) {
      const int hp = h - 1;
      {
        const u64 qA = __builtin_bit_cast(u64, Qprev[0]);
        const u64 qB = __builtin_bit_cast(u64, Qprev[1]);
        u64 A0 = __shfl(qA, l16 + qs), A1 = __shfl(qA, l16 + qs + 16);
        u64 B0 = __shfl(qB, l16 + qs), B1 = __shfl(qB, l16 + qs + 16);
        v4bf lo = __builtin_bit_cast(v4bf, (quad >> 1) ? B0 : A0);
        v4bf hi = __builtin_bit_cast(v4bf, (quad >> 1) ? B1 : A1);
        v8bf a_fc;
#pragma unroll
        for (int r = 0; r < 4; ++r) { a_fc[r] = lo[r]; a_fc[4 + r] = hi[r]; }
#pragma unroll
        for (int nt = 0; nt < 4; ++nt)
          acc[nt] = __builtin_amdgcn_mfma_f32_16x16x32_bf16(a_fc, wf0[nt], acc[nt], 0, 0, 0);
      }
      {
        const u64 qA = __builtin_bit_cast(u64, Qprev[2]);
        const u64 qB = __builtin_bit_cast(u64, Qprev[3]);
        u64 A0 = __shfl(qA, l16 + qs), A1 = __shfl(qA, l16 + qs + 16);
        u64 B0 = __shfl(qB, l16 + qs), B1 = __shfl(qB, l16 + qs + 16);
        v4bf lo = __builtin_bit_cast(v4bf, (quad >> 1) ? B0 : A0);
        v4bf hi = __builtin_bit_cast(v4bf, (quad >> 1) ? B1 : A1);
        v8bf a_fc;
#pragma unroll
        for (int r = 0; r < 4; ++r) { a_fc[r] = lo[r]; a_fc[4 + r] = hi[r]; }
#pragma unroll
        for (int nt = 0; nt < 4; ++nt) {
          v8bf bb = *(const v8bf*)(wfc + (size_t)(nt * 16 + hp * 2 + 1) * 512 + l16 * 32 + 8 * quad);
          acc[nt] = __builtin_amdgcn_mfma_f32_16x16x32_bf16(a_fc, bb, acc[nt], 0, 0, 0);
        }
      }
    }

    // ---- next head's gather from s_feat (latency hidden under bar2 + stage + PV)
    if (it < 3) {
      g0[0] = s_feat[ixn[0].x]; g0[1] = s_feat[ixn[0].y];
      g0[2] = s_feat[ixn[0].z]; g0[3] = s_feat[ixn[0].w];
      g0[4] = s_feat[ixn[1].x]; g0[5] = s_feat[ixn[1].y];
      g0[6] = s_feat[ixn[1].z]; g0[7] = s_feat[ixn[1].w];
      g1[0] = s_feat[ixn[2].x]; g1[1] = s_feat[ixn[2].y];
      g1[2] = s_feat[ixn[2].z]; g1[3] = s_feat[ixn[2].w];
      g1[4] = s_feat[ixn[3].x]; g1[5] = s_feat[ixn[3].y];
      g1[6] = s_feat[ixn[3].z]; g1[7] = s_feat[ixn[3].w];
    }
    __syncthreads();  // bar2: s_vT ready; all s_kf readers (conv) done

    // ---- software pipeline: stage(h+1) issues BEFORE PV(h)
    // legal: s_kf has no readers until after next bar1; s_K goes to the other buffer;
    // PV below reads s_vT(h), which conv(h+1) only rewrites after bar1(h+1).
    if (it < 3) stage(h + 1, (it & 1) ? s_K0 : s_K1);

    // ---- PV: swapped, dOT[st] = o[qi=myrow][s=16st+4quad+r] (row-local)
    v4f dOT[4] = {{0.f, 0.f, 0.f, 0.f}, {0.f, 0.f, 0.f, 0.f},
                  {0.f, 0.f, 0.f, 0.f}, {0.f, 0.f, 0.f, 0.f}};
#pragma unroll
    for (int kt = 0; kt < 2; ++kt) {
      const u64 pA = __builtin_bit_cast(u64, P[2 * kt]);
      const u64 pB = __builtin_bit_cast(u64, P[2 * kt + 1]);
      u64 A0 = __shfl(pA, l16 + qs), A1 = __shfl(pA, l16 + qs + 16);
      u64 B0 = __shfl(pB, l16 + qs), B1 = __shfl(pB, l16 + qs + 16);
      v4bf lo = __builtin_bit_cast(v4bf, (quad >> 1) ? B0 : A0);
      v4bf hi = __builtin_bit_cast(v4bf, (quad >> 1) ? B1 : A1);
      v8bf a_pv;
#pragma unroll
      for (int r = 0; r < 4; ++r) { a_pv[r] = lo[r]; a_pv[4 + r] = hi[r]; }
#pragma unroll
      for (int st = 0; st < 4; ++st) {
        v8bf bb = *(const v8bf*)(s_vT + (16 * st + l16) * 72 + 32 * kt + 8 * quad);
        dOT[st] = __builtin_amdgcn_mfma_f32_16x16x32_bf16(bb, a_pv, dOT[st], 0, 0, 0);
      }
    }
    // pack o for fc (consumed next iteration / after loop)
#pragma unroll
    for (int st = 0; st < 4; ++st)
#pragma unroll
      for (int r = 0; r < 4; ++r) Qprev[st][r] = (__bf16)dOT[st][r];
  }

  // ---- fc for last head
  {
    const int hp = h0 + 3;
#pragma unroll
    for (int kt = 0; kt < 2; ++kt) {
      const u64 qA = __builtin_bit_cast(u64, Qprev[2 * kt]);
      const u64 qB = __builtin_bit_cast(u64, Qprev[2 * kt + 1]);
      u64 A0 = __shfl(qA, l16 + qs), A1 = __shfl(qA, l16 + qs + 16);
      u64 B0 = __shfl(qB, l16 + qs), B1 = __shfl(qB, l16 + qs + 16);
      v4bf lo = __builtin_bit_cast(v4bf, (quad >> 1) ? B0 : A0);
      v4bf hi = __builtin_bit_cast(v4bf, (quad >> 1) ? B1 : A1);
      v8bf a_fc;
#pragma unroll
      for (int r = 0; r < 4; ++r) { a_fc[r] = lo[r]; a_fc[4 + r] = hi[r]; }
#pragma unroll
      for (int nt = 0; nt < 4; ++nt) {
        v8bf bb = *(const v8bf*)(wfc + (size_t)(nt * 16 + hp * 2 + kt) * 512 + l16 * 32 + 8 * quad);
        acc[nt] = __builtin_amdgcn_mfma_f32_16x16x32_bf16(a_fc, bb, acc[nt], 0, 0, 0);
      }
    }
  }

  // ---- combine fc partials across the two half-blocks via atomicAdd (out pre-zeroed by k0)
  float* orow = out + (size_t)b * kM;
#pragma unroll
  for (int nt = 0; nt < 4; ++nt)
#pragma unroll
    for (int r = 0; r < 4; ++r)
      atomicAdd(&orow[(16 * w + 4 * quad + r) * 64 + 16 * nt + l16], acc[nt][r]);
}

}  // namespace

extern "C" void kernel_launch(void* const* d_in, const int* in_sizes, int n_in,
                              void* d_out, int out_size, void* d_ws, size_t ws_size,
                              hipStream_t stream) {
  (void)in_sizes; (void)n_in; (void)out_size; (void)ws_size;
  const float* features = (const float*)d_in[0];
  const int*   sidx     = (const int*)d_in[1];
  const float* gamma    = (const float*)d_in[2];
  const float* beta     = (const float*)d_in[3];
  const float* Wq       = (const float*)d_in[4];
  const float* Wk       = (const float*)d_in[5];
  const float* Wv1      = (const float*)d_in[6];
  const float* Wv2      = (const float*)d_in[7];
  const float* Wfc      = (const float*)d_in[8];
  float* out = (float*)d_out;

  char* ws = (char*)d_ws;
  __bf16* ws_wq  = (__bf16*)(ws);
  __bf16* ws_wk  = (__bf16*)(ws + 32768);
  __bf16* ws_wfc = (__bf16*)(ws + 65536);

  hipLaunchKernelGGL(k0_weights, dim3(512), dim3(256), 0, stream,
                     Wq, Wk, Wfc, ws_wq, ws_wk, ws_wfc, out);
  hipLaunchKernelGGL(k_fused, dim3(kB, 2), dim3(256), 0, stream,
                     features, sidx, gamma, beta, ws_wq, ws_wk, Wv1, Wv2, ws_wfc, out);
}